// Round 3
// baseline (686.583 us; speedup 1.0000x reference)
//
#include <hip/hip_runtime.h>
#include <hip/hip_bf16.h>

// Problem: G=16 groups, B=8192 rows, K=1024 centroids, D=64.
// out[g][b][k] = || x[g][b][:] - c[g][k][:] ||_2  (fp32 in / fp32 out)
// Strategy: d2 = x2 + c2 - 2*dot; dot via f16 split-precision MFMA
// (x = xh + xl, c = ch + cl; dot ~= xh.ch + xh.cl + xl.ch, fp32 accumulate).
// RN split -> error ~2^-22 relative, far below fp32 check tolerance.
// Inputs (36 MiB total, 2.25 MiB/group) are L2-resident: NO LDS staging
// (Common-mistake #7). Bottleneck is the 512 MiB output write stream.

#define GG 16
#define BB 8192
#define KK 1024
#define DD 64

typedef float    floatx4 __attribute__((ext_vector_type(4)));
typedef _Float16 half8   __attribute__((ext_vector_type(8)));

// Load 8 consecutive fp32 (32B aligned) and split into f16 hi + f16 lo.
__device__ __forceinline__ void split8(const float* __restrict__ p,
                                       half8& hi, half8& lo) {
  floatx4 a = *(const floatx4*)p;
  floatx4 b = *(const floatx4*)(p + 4);
  float v[8] = {a[0], a[1], a[2], a[3], b[0], b[1], b[2], b[3]};
#pragma unroll
  for (int i = 0; i < 8; ++i) {
    _Float16 h = (_Float16)v[i];          // v_cvt_f16_f32 (RN)
    hi[i] = h;
    lo[i] = (_Float16)(v[i] - (float)h);  // residual fits f16 exactly-ish
  }
}

// 128x128 output tile per block. 256 threads = 4 waves in 2x2; each wave owns
// a 64x64 subtile = 4x4 fragments of 16x16. D=64 -> 2 k-steps of 32, no K-loop.
__global__ __launch_bounds__(256, 2) void dist_kernel(
    const float* __restrict__ x, const float* __restrict__ cen,
    float* __restrict__ out) {
  const int g   = blockIdx.z;
  const int bm0 = blockIdx.y * 128;
  const int bn0 = blockIdx.x * 128;
  const float* Xg = x   + (size_t)g * BB * DD;
  const float* Cg = cen + (size_t)g * KK * DD;
  float*       Og = out + (size_t)g * BB * KK;

  // --- exact fp32 row/col norms into LDS (once per block) ---
  __shared__ float sx2[128];
  __shared__ float sc2[128];
  const int tid = threadIdx.x;
  {
    const float* p = (tid < 128) ? (Xg + (size_t)(bm0 + tid) * DD)
                                 : (Cg + (size_t)(bn0 + (tid - 128)) * DD);
    floatx4 s = {0.f, 0.f, 0.f, 0.f};
#pragma unroll
    for (int i = 0; i < 16; ++i) {
      floatx4 v = ((const floatx4*)p)[i];
      s += v * v;
    }
    float r = s[0] + s[1] + s[2] + s[3];
    if (tid < 128) sx2[tid] = r; else sc2[tid - 128] = r;
  }

  const int lane = tid & 63;
  const int w    = tid >> 6;
  const int wr   = w >> 1, wc = w & 1;      // 2x2 wave grid
  const int l16  = lane & 15, lq = lane >> 4;

  // --- A fragments (X rows), held in registers across the n-loop ---
  half8 ah[4][2], al[4][2];
#pragma unroll
  for (int m = 0; m < 4; ++m) {
#pragma unroll
    for (int kq = 0; kq < 2; ++kq) {
      int row = bm0 + wr * 64 + m * 16 + l16;
      split8(Xg + (size_t)row * DD + kq * 32 + lq * 8, ah[m][kq], al[m][kq]);
    }
  }

  floatx4 acc[4][4];
#pragma unroll
  for (int m = 0; m < 4; ++m)
#pragma unroll
    for (int n = 0; n < 4; ++n) acc[m][n] = (floatx4){0.f, 0.f, 0.f, 0.f};

#pragma unroll
  for (int n = 0; n < 4; ++n) {
    half8 bh[2], bl[2];
#pragma unroll
    for (int kq = 0; kq < 2; ++kq) {
      int col = bn0 + wc * 64 + n * 16 + l16;
      split8(Cg + (size_t)col * DD + kq * 32 + lq * 8, bh[kq], bl[kq]);
    }
#pragma unroll
    for (int m = 0; m < 4; ++m) {
#pragma unroll
      for (int kq = 0; kq < 2; ++kq) {
        acc[m][n] = __builtin_amdgcn_mfma_f32_16x16x32_f16(ah[m][kq], bh[kq], acc[m][n], 0, 0, 0);
        acc[m][n] = __builtin_amdgcn_mfma_f32_16x16x32_f16(ah[m][kq], bl[kq], acc[m][n], 0, 0, 0);
        acc[m][n] = __builtin_amdgcn_mfma_f32_16x16x32_f16(al[m][kq], bh[kq], acc[m][n], 0, 0, 0);
      }
    }
  }

  __syncthreads();  // sx2/sc2 ready (written at top by all threads)

  // --- epilogue: d = sqrt(max(x2 + c2 - 2*dot, 0)) ---
  // C/D layout (verified m89/m91): col = lane&15, row = (lane>>4)*4 + reg.
  float c2r[4];
#pragma unroll
  for (int n = 0; n < 4; ++n) c2r[n] = sc2[wc * 64 + n * 16 + l16];

#pragma unroll
  for (int m = 0; m < 4; ++m) {
#pragma unroll
    for (int j = 0; j < 4; ++j) {
      const int rl = wr * 64 + m * 16 + lq * 4 + j;
      const float x2r = sx2[rl];
      float* orow = Og + (size_t)(bm0 + rl) * KK + bn0 + wc * 64 + l16;
#pragma unroll
      for (int n = 0; n < 4; ++n) {
        float d2 = fmaf(-2.0f, acc[m][n][j], x2r + c2r[n]);
        // write-once stream: nontemporal keeps inputs hot in L2
        __builtin_nontemporal_store(sqrtf(fmaxf(d2, 0.0f)), orow + n * 16);
      }
    }
  }
}

extern "C" void kernel_launch(void* const* d_in, const int* in_sizes, int n_in,
                              void* d_out, int out_size, void* d_ws, size_t ws_size,
                              hipStream_t stream) {
  const float* x   = (const float*)d_in[0];
  const float* cen = (const float*)d_in[1];
  float* out = (float*)d_out;
  dim3 grid(KK / 128, BB / 128, GG);  // (n-tiles, m-tiles, groups) = (8, 64, 16)
  dist_kernel<<<grid, dim3(256), 0, stream>>>(x, cen, out);
}

// Round 4
// 679.497 us; speedup vs baseline: 1.0104x; 1.0104x over previous
//
#include <hip/hip_runtime.h>
#include <hip/hip_bf16.h>

// Problem: G=16 groups, B=8192 rows, K=1024 centroids, D=64.
// out[g][b][k] = || x[g][b][:] - c[g][k][:] ||_2  (fp32 in / fp32 out)
// d2 = x2 + c2 - 2*dot; dot via f16 split-precision MFMA
// (x = xh+xl, c = ch+cl; dot ~= ch.xh + ch.xl + cl.xh, fp32 accumulate).
//
// Round-4 change: OPERANDS SWAPPED vs round 3 — mfma(A=centroid, B=x) puts a
// lane's 4 acc regs on 4 CONSECUTIVE centroid columns (C/D map: col=lane&15
// -> x row, row=(lane>>4)*4+reg -> centroid). Epilogue becomes 16x
// global_store_dwordx4 per thread (was 64 scalar nt-stores whose 64B partial
// lines forced HBM read-modify-write). Plain stores: L2 write-allocate merges
// into full lines (fills sustain 6.3 TB/s this way).

#define GG 16
#define BB 8192
#define KK 1024
#define DD 64

typedef float    floatx4 __attribute__((ext_vector_type(4)));
typedef _Float16 half8   __attribute__((ext_vector_type(8)));

// Load 8 consecutive fp32 (32B aligned) and split into f16 hi + f16 lo (RN).
__device__ __forceinline__ void split8(const float* __restrict__ p,
                                       half8& hi, half8& lo) {
  floatx4 a = *(const floatx4*)p;
  floatx4 b = *(const floatx4*)(p + 4);
  float v[8] = {a[0], a[1], a[2], a[3], b[0], b[1], b[2], b[3]};
#pragma unroll
  for (int i = 0; i < 8; ++i) {
    _Float16 h = (_Float16)v[i];          // v_cvt_f16_f32 (RN)
    hi[i] = h;
    lo[i] = (_Float16)(v[i] - (float)h);
  }
}

// 128x128 output tile per block. 256 threads = 4 waves in 2x2; each wave owns
// a 64x64 subtile. D=64 -> 2 k-steps of 32, no K-loop, no LDS staging
// (inputs are 2.25 MiB/group -> L2/L3-resident).
__global__ __launch_bounds__(256, 2) void dist_kernel(
    const float* __restrict__ x, const float* __restrict__ cen,
    float* __restrict__ out) {
  const int g   = blockIdx.z;
  const int bm0 = blockIdx.y * 128;
  const int bn0 = blockIdx.x * 128;
  const float* Xg = x   + (size_t)g * BB * DD;
  const float* Cg = cen + (size_t)g * KK * DD;
  float*       Og = out + (size_t)g * BB * KK;

  // --- exact fp32 row/col norms into LDS (once per block) ---
  __shared__ __align__(16) float sx2[128];
  __shared__ __align__(16) float sc2[128];
  const int tid = threadIdx.x;
  {
    const float* p = (tid < 128) ? (Xg + (size_t)(bm0 + tid) * DD)
                                 : (Cg + (size_t)(bn0 + (tid - 128)) * DD);
    floatx4 s = {0.f, 0.f, 0.f, 0.f};
#pragma unroll
    for (int i = 0; i < 16; ++i) {
      floatx4 v = ((const floatx4*)p)[i];
      s += v * v;
    }
    float r = s[0] + s[1] + s[2] + s[3];
    if (tid < 128) sx2[tid] = r; else sc2[tid - 128] = r;
  }

  const int lane = tid & 63;
  const int w    = tid >> 6;
  const int wr   = w >> 1, wc = w & 1;      // 2x2 wave grid
  const int l16  = lane & 15, lq = lane >> 4;

  // --- centroid fragments = MFMA A operand, held across the m-loop ---
  half8 ch[4][2], cl[4][2];
#pragma unroll
  for (int n = 0; n < 4; ++n) {
#pragma unroll
    for (int kq = 0; kq < 2; ++kq) {
      int row = bn0 + wc * 64 + n * 16 + l16;
      split8(Cg + (size_t)row * DD + kq * 32 + lq * 8, ch[n][kq], cl[n][kq]);
    }
  }

  floatx4 acc[4][4];
#pragma unroll
  for (int m = 0; m < 4; ++m)
#pragma unroll
    for (int n = 0; n < 4; ++n) acc[m][n] = (floatx4){0.f, 0.f, 0.f, 0.f};

#pragma unroll
  for (int m = 0; m < 4; ++m) {
    half8 xh[2], xl[2];
#pragma unroll
    for (int kq = 0; kq < 2; ++kq) {
      int row = bm0 + wr * 64 + m * 16 + l16;
      split8(Xg + (size_t)row * DD + kq * 32 + lq * 8, xh[kq], xl[kq]);
    }
#pragma unroll
    for (int n = 0; n < 4; ++n) {
#pragma unroll
      for (int kq = 0; kq < 2; ++kq) {
        acc[m][n] = __builtin_amdgcn_mfma_f32_16x16x32_f16(ch[n][kq], xh[kq], acc[m][n], 0, 0, 0);
        acc[m][n] = __builtin_amdgcn_mfma_f32_16x16x32_f16(ch[n][kq], xl[kq], acc[m][n], 0, 0, 0);
        acc[m][n] = __builtin_amdgcn_mfma_f32_16x16x32_f16(cl[n][kq], xh[kq], acc[m][n], 0, 0, 0);
      }
    }
  }

  __syncthreads();  // sx2/sc2 ready (written at top by all threads)

  // --- epilogue: d = sqrt(max(x2 + c2 - 2*dot, 0)), dwordx4 stores ---
  // D[i=centroid][j=x_row]; C/D map: col=lane&15 -> x row, row=lq*4+reg ->
  // centroid. A lane's 4 regs = 4 consecutive centroid columns.
#pragma unroll
  for (int m = 0; m < 4; ++m) {
    const int   rloc = wr * 64 + m * 16 + l16;   // x row within tile
    const float x2r  = sx2[rloc];
    float* orow = Og + (size_t)(bm0 + rloc) * KK + bn0;
#pragma unroll
    for (int n = 0; n < 4; ++n) {
      const int c0 = wc * 64 + n * 16 + lq * 4;  // centroid col base (16B-aligned)
      floatx4 c2v = *(const floatx4*)&sc2[c0];
      floatx4 r;
#pragma unroll
      for (int j = 0; j < 4; ++j) {
        float d2 = fmaf(-2.0f, acc[m][n][j], x2r + c2v[j]);
        r[j] = sqrtf(fmaxf(d2, 0.0f));
      }
      *(floatx4*)(orow + c0) = r;
    }
  }
}

extern "C" void kernel_launch(void* const* d_in, const int* in_sizes, int n_in,
                              void* d_out, int out_size, void* d_ws, size_t ws_size,
                              hipStream_t stream) {
  const float* x   = (const float*)d_in[0];
  const float* cen = (const float*)d_in[1];
  float* out = (float*)d_out;
  dim3 grid(KK / 128, BB / 128, GG);  // (n-tiles, m-tiles, groups) = (8, 64, 16)
  dist_kernel<<<grid, dim3(256), 0, stream>>>(x, cen, out);
}